// Round 2
// baseline (114.080 us; speedup 1.0000x reference)
//
#include <hip/hip_runtime.h>

#define BB 512
#define LL 100
#define DLEN 100000
// MARGIN = 1.0f, GAMMA = 0.9f (float(1-0.9) rounds to 0.1f)

__global__ __launch_bounds__(BB) void map_loss_rows(
    const float* __restrict__ y_pred,   // (B, L) row-major
    const float* __restrict__ y_true,   // (B, L)
    const int*   __restrict__ index,    // (B,)
    const float* __restrict__ u_all,    // (L, DLEN, 1)
    const float* __restrict__ u_pos,    // (L, DLEN, 1)
    double*      __restrict__ per_label // (L,) in workspace
) {
    const int l = blockIdx.x;   // label
    const int i = threadIdx.x;  // row index within label

    __shared__ float fp_s[BB];
    __shared__ float pos_s[BB];

    const float xi = y_pred[(size_t)i * LL + l];          // fp[l, i] = y_pred[i, l]
    const float pi = (y_true[(size_t)i * LL + l] == 1.0f) ? 1.0f : 0.0f;
    fp_s[i]  = xi;
    pos_s[i] = pi;
    __syncthreads();

    // S = sum_j sur(i,j), SP = sum_j sur(i,j)*pos[j]
    float S = 0.0f, SP = 0.0f;
#pragma unroll 8
    for (int j = 0; j < BB; ++j) {
        const float d  = xi - fp_s[j];          // diff
        const float m  = 1.0f - d;              // MARGIN - diff
        const float mm = fmaxf(m, 0.0f);
        const float s  = mm * mm;               // sur
        S  += s;
        SP += s * pos_s[j];
    }

    // contribution of row i (zero when pos_i == 0, matching pos[:, :, None] mask)
    double c = 0.0;
    if (pi > 0.0f) {
        const float row_mean     = S  * (1.0f / BB);
        const float pos_row_mean = SP * (1.0f / BB);
        const int   idx = index[i];
        const float ua  = u_all[(size_t)l * DLEN + idx];
        const float up  = u_pos[(size_t)l * DLEN + idx];
        const float ua_new = 0.1f * ua + 0.9f * row_mean;     // (1-GAMMA)*ua + GAMMA*row_mean
        const float up_new = 0.1f * up + 0.9f * pos_row_mean;
        // sum_j p_i*sur = (up_new*S - ua_new*SP) / ua_new^2   (denom = ua_new since pos_i>0)
        c = (double)((up_new * S - ua_new * SP) / (ua_new * ua_new));
    }

    // block reduce (c, n_pos) over 512 threads = 8 waves
    double npos = (double)pi;
    for (int off = 32; off > 0; off >>= 1) {
        c    += __shfl_down(c, off, 64);
        npos += __shfl_down(npos, off, 64);
    }
    __shared__ double red_c[8];
    __shared__ double red_n[8];
    const int wave = i >> 6;
    const int lane = i & 63;
    if (lane == 0) { red_c[wave] = c; red_n[wave] = npos; }
    __syncthreads();
    if (i == 0) {
        double cs = 0.0, ns = 0.0;
#pragma unroll
        for (int w = 0; w < 8; ++w) { cs += red_c[w]; ns += red_n[w]; }
        per_label[l] = cs / (ns * (double)BB);  // sum/(n_pos*b)
    }
}

__global__ __launch_bounds__(128) void map_loss_final(
    const double* __restrict__ per_label, float* __restrict__ out) {
    const int t = threadIdx.x;
    double v = (t < LL) ? per_label[t] : 0.0;
    for (int off = 32; off > 0; off >>= 1) v += __shfl_down(v, off, 64);
    __shared__ double tmp[2];
    if ((t & 63) == 0) tmp[t >> 6] = v;
    __syncthreads();
    if (t == 0) out[0] = (float)((tmp[0] + tmp[1]) / (double)LL);
}

extern "C" void kernel_launch(void* const* d_in, const int* in_sizes, int n_in,
                              void* d_out, int out_size, void* d_ws, size_t ws_size,
                              hipStream_t stream) {
    const float* y_pred = (const float*)d_in[0];
    const float* y_true = (const float*)d_in[1];
    const int*   index  = (const int*)d_in[2];
    const float* u_all  = (const float*)d_in[3];
    const float* u_pos  = (const float*)d_in[4];

    double* per_label = (double*)d_ws;   // 100 doubles
    float*  out       = (float*)d_out;   // scalar loss

    map_loss_rows<<<LL, BB, 0, stream>>>(y_pred, y_true, index, u_all, u_pos, per_label);
    map_loss_final<<<1, 128, 0, stream>>>(per_label, out);
}

// Round 3
// 113.406 us; speedup vs baseline: 1.0059x; 1.0059x over previous
//
#include <hip/hip_runtime.h>

#define BB 512
#define LL 100
#define DLEN 100000
// MARGIN = 1.0f, GAMMA = 0.9f

// One block per label. 1024 threads: 2 threads per row i (t>>1), each covers
// half of the j-loop (256 iters), combined with one __shfl_xor. Per-block
// result is atomically accumulated into out[0] (pre-zeroed via memsetAsync);
// 100 float atomic adds of ~1e-2 magnitude -> reassociation error ~1e-7,
// threshold is 2.8e-4.
__global__ __launch_bounds__(1024) void map_loss_fused(
    const float* __restrict__ y_pred,   // (B, L)
    const float* __restrict__ y_true,   // (B, L)
    const int*   __restrict__ index,    // (B,)
    const float* __restrict__ u_all,    // (L, DLEN, 1)
    const float* __restrict__ u_pos,    // (L, DLEN, 1)
    float*       __restrict__ out)      // scalar, pre-zeroed
{
    const int l = blockIdx.x;
    const int t = threadIdx.x;
    const int i = t >> 1;     // row
    const int h = t & 1;      // j-half

    __shared__ float fp_s[BB];
    __shared__ float pos_s[BB];

    if (t < BB) {
        fp_s[t]  = y_pred[(size_t)t * LL + l];                    // fp[l, t]
        pos_s[t] = (y_true[(size_t)t * LL + l] == 1.0f) ? 1.0f : 0.0f;
    }
    __syncthreads();

    const float xi = fp_s[i];
    const float pi = pos_s[i];
    const float tm = 1.0f - xi;   // so (MARGIN - diff) = tm + fp_s[j]

    float S = 0.0f, SP = 0.0f;
    const int j0 = h * (BB / 2);
#pragma unroll 8
    for (int j = j0; j < j0 + BB / 2; ++j) {
        const float m  = tm + fp_s[j];
        const float mm = fmaxf(m, 0.0f);
        const float s  = mm * mm;
        S  += s;
        SP += s * pos_s[j];
    }
    // lanes t and t^1 are in the same wave: combine the two j-halves
    S  += __shfl_xor(S, 1, 64);
    SP += __shfl_xor(SP, 1, 64);

    // contribution of row i (count it once: h==0 lane only)
    double c = 0.0, npos = 0.0;
    if (h == 0) {
        npos = (double)pi;
        if (pi > 0.0f) {
            const float row_mean     = S  * (1.0f / BB);
            const float pos_row_mean = SP * (1.0f / BB);
            const int   idx = index[i];
            const float ua  = u_all[(size_t)l * DLEN + idx];
            const float up  = u_pos[(size_t)l * DLEN + idx];
            const float ua_new = 0.1f * ua + 0.9f * row_mean;
            const float up_new = 0.1f * up + 0.9f * pos_row_mean;
            // sum_j p_i*sur = (up_new*S - ua_new*SP) / ua_new^2
            c = (double)((up_new * S - ua_new * SP) / (ua_new * ua_new));
        }
    }

    // block reduction of (c, npos) over 16 waves
    for (int off = 32; off > 0; off >>= 1) {
        c    += __shfl_down(c, off, 64);
        npos += __shfl_down(npos, off, 64);
    }
    __shared__ double red_c[16];
    __shared__ double red_n[16];
    const int wave = t >> 6;
    if ((t & 63) == 0) { red_c[wave] = c; red_n[wave] = npos; }
    __syncthreads();
    if (t == 0) {
        double cs = 0.0, ns = 0.0;
#pragma unroll
        for (int w = 0; w < 16; ++w) { cs += red_c[w]; ns += red_n[w]; }
        // per_label / (n_pos * B), then mean over L labels
        const float contrib = (float)(cs / (ns * (double)BB) / (double)LL);
        atomicAdd(out, contrib);
    }
}

extern "C" void kernel_launch(void* const* d_in, const int* in_sizes, int n_in,
                              void* d_out, int out_size, void* d_ws, size_t ws_size,
                              hipStream_t stream) {
    const float* y_pred = (const float*)d_in[0];
    const float* y_true = (const float*)d_in[1];
    const int*   index  = (const int*)d_in[2];
    const float* u_all  = (const float*)d_in[3];
    const float* u_pos  = (const float*)d_in[4];
    float* out = (float*)d_out;

    hipMemsetAsync(out, 0, sizeof(float), stream);
    map_loss_fused<<<LL, 1024, 0, stream>>>(y_pred, y_true, index, u_all, u_pos, out);
}